// Round 3
// baseline (1639.255 us; speedup 1.0000x reference)
//
#include <hip/hip_runtime.h>
#include <math.h>

typedef unsigned short u16;
typedef unsigned int   u32;

#define LVLS 24
#define CAPN (1 << 18)
#define STR  81           // LDS act row stride in u32 (odd => benign bank pattern)

typedef float    f32x4 __attribute__((ext_vector_type(4)));
typedef _Float16 f16x8 __attribute__((ext_vector_type(8)));

#if __has_builtin(__builtin_amdgcn_rcpf)
#define RCPF(x) __builtin_amdgcn_rcpf(x)
#else
#define RCPF(x) (1.0f / (x))
#endif
#if __has_builtin(__builtin_amdgcn_exp2f)
#define EXP2F(x) __builtin_amdgcn_exp2f(x)
#else
#define EXP2F(x) exp2f(x)
#endif

// ---- global scaling scheme (fp16-denormal avoidance; verified abs=3.9e-3) ----
// B side (activations / pos / SH / hash feats) stored as 256*x in fp16 hi/lo.
// A side (weights) converted on the fly to 256*w in fp16 hi/lo.
// MFMA acc = 65536 * (x.w); epilogue descales via fmaf(d, 2^-16, bias).
//
// SELF-CONTAINED: single kernel, reads ONLY d_in, writes ONLY d_out.
// No d_ws use at all — the prior 3-dispatch version produced correct output
// on the first call but diverged (to the exact lo-data-lost error floor,
// 1.95e-2) on graph replays: a cross-dispatch d_ws hazard under the
// harness's workspace re-poisoning. Weight fragments are now built
// in-register from d_in each layer; hash encode is inlined.

__device__ __forceinline__ float h2f(u16 b) {
    union { u16 u; _Float16 h; } v; v.u = b; return (float)v.h;
}
__device__ __forceinline__ u16 f2h(float x) {
    union { _Float16 h; u16 u; } v; v.h = (_Float16)x; return v.u;   // RNE v_cvt_f16_f32
}
__device__ __forceinline__ void hsplit(float x, u16& h, u16& l) {
    h = f2h(x);
    float r = x - h2f(h);
    l = f2h(r);
}
__device__ __forceinline__ u32 packhl(float x) {
    u16 h, l; hsplit(x, h, l);
    return ((u32)h << 16) | l;
}
__device__ __forceinline__ float unpackhl(u32 w) {
    return h2f((u16)(w >> 16)) + h2f((u16)(w & 0xffffu));
}
// A&S 7.1.26 erf (|eps|<=1.5e-7), hw rcp + exp2
__device__ __forceinline__ float gelu_f(float x) {
    float z  = fabsf(x) * 0.70710678118654752f;
    float t  = RCPF(fmaf(0.3275911f, z, 1.0f));
    float e  = EXP2F(-z * z * 1.44269504088896340f);
    float p  = fmaf(1.061405429f, t, -1.453152027f);
    p = fmaf(p, t, 1.421413741f);
    p = fmaf(p, t, -0.284496736f);
    p = fmaf(p, t, 0.254829592f);
    p = p * t;
    float erfv = fmaf(-p, e, 1.0f);
    float se   = copysignf(erfv, x);
    return x * fmaf(0.5f, se, 0.5f);
}
__device__ __forceinline__ float sigmoid_f(float y) {
    return RCPF(1.0f + EXP2F(-y * 1.44269504088896340f));
}
__device__ __forceinline__ f16x8 cast8h(u32 a, u32 b, u32 c, u32 d) {
    union { u32 u[4]; f16x8 h; } v; v.u[0]=a; v.u[1]=b; v.u[2]=c; v.u[3]=d; return v.h;
}
__device__ __forceinline__ void window_scale(int l, const int* iter, float& sc, float& wl) {
    sc = powf(10.0f, (float)l * (-4.0f / 23.0f));
    double itd = (double)iter[0] / 10000.0;
    itd = itd < 0.0 ? 0.0 : (itd > 1.0 ? 1.0 : itd);
    float tL = (float)((0.3 + 0.7 * itd) * 24.0);
    float arg = fminf(fmaxf(tL - (float)l, 0.0f), 1.0f);
    wl = 0.5f - 0.5f * cosf(3.14159265358979323846f * arg);
}
// 8-corner hash interp for one (point, level) -> f0, f1 (window applied)
__device__ __forceinline__ void hash_level(float px, float py, float pz, float sc, float wl,
                                           int sx, int sy, int sz,
                                           const float* __restrict__ tl,
                                           float& f0, float& f1) {
    float cx = px / sc, cy = py / sc, cz = pz / sc;
    float fx = floorf(cx), fy = floorf(cy), fz = floorf(cz);
    float rx = cx - fx, ry = cy - fy, rz = cz - fz;
    int bx = (int)fx + sx, by = (int)fy + sy, bz = (int)fz + sz;
    u32 hx0 = (u32)bx, hx1 = (u32)(bx + 1);
    u32 hy0 = (u32)by * 2654435761u, hy1 = (u32)(by + 1) * 2654435761u;
    u32 hz0 = (u32)bz * 805459861u,  hz1 = (u32)(bz + 1) * 805459861u;
    float a0 = 0.f, a1 = 0.f;
    #pragma unroll
    for (int c = 0; c < 8; c++) {
        u32 hx = (c & 1) ? hx1 : hx0;
        u32 hy = (c & 2) ? hy1 : hy0;
        u32 hz = (c & 4) ? hz1 : hz0;
        u32 idx = (hx ^ hy ^ hz) & (CAPN - 1);
        float w = ((c & 1) ? rx : 1.0f - rx);
        w *= ((c & 2) ? ry : 1.0f - ry);
        w *= ((c & 4) ? rz : 1.0f - rz);
        const float* tf = tl + 2 * (size_t)idx;
        a0 = fmaf(w, tf[0], a0);
        a1 = fmaf(w, tf[1], a1);
    }
    f0 = a0 * wl;
    f1 = a1 * wl;
}

// ============ MFMA layer: weights converted in-register from fp32 d_in ============
// W row-major [Ksrc][ldm], output col m = it*16 + r + coloff.
// D[outfeat][point] = (256 W) * (256 X) with fp16 hi/lo 3-product scheme.
template <int NKT, bool SHT>
__device__ __forceinline__ void mfma_layer(const float* __restrict__ W, int Ksrc, int ldm, int coloff,
                                           const u32* act, int lane, f32x4 acc[4][4]) {
    const int q = lane >> 4, r = lane & 15;
    #pragma unroll
    for (int jt = 0; jt < 4; jt++)
        #pragma unroll
        for (int it = 0; it < 4; it++)
            acc[jt][it] = (f32x4){0.f, 0.f, 0.f, 0.f};
    #pragma unroll
    for (int kt = 0; kt < NKT; kt++) {
        f16x8 whi[4], wlo[4];
        #pragma unroll
        for (int it = 0; it < 4; it++) {
            const int m  = it * 16 + r + coloff;
            const int k0 = kt * 32 + q * 8;
            #pragma unroll
            for (int e = 0; e < 8; e++) {
                int k = k0 + e;
                float w = (k < Ksrc) ? W[(size_t)k * ldm + m] * 256.0f : 0.0f;
                u16 hh, ll; hsplit(w, hh, ll);
                union { u16 u; _Float16 h; } ch, cl; ch.u = hh; cl.u = ll;
                whi[it][e] = ch.h;
                wlo[it][e] = cl.h;
            }
        }
        #pragma unroll
        for (int jt = 0; jt < 4; jt++) {
            bool zero = SHT && (kt == NKT - 1) && (q >= 2);
            const u32* rowp = act + (jt * 16 + r) * STR + kt * 32 + q * 8;
            u32 v[8];
            #pragma unroll
            for (int e = 0; e < 8; e++) v[e] = zero ? 0u : rowp[e];
            u32 xh[4], xl[4];
            #pragma unroll
            for (int j2 = 0; j2 < 4; j2++) {
                xh[j2] = (v[2*j2] >> 16) | (v[2*j2+1] & 0xffff0000u);
                xl[j2] = (v[2*j2] & 0xffffu) | (v[2*j2+1] << 16);
            }
            f16x8 bh = cast8h(xh[0], xh[1], xh[2], xh[3]);
            f16x8 bl = cast8h(xl[0], xl[1], xl[2], xl[3]);
            #pragma unroll
            for (int it = 0; it < 4; it++) {
                acc[jt][it] = __builtin_amdgcn_mfma_f32_16x16x32_f16(whi[it], bh, acc[jt][it], 0, 0, 0);
                acc[jt][it] = __builtin_amdgcn_mfma_f32_16x16x32_f16(whi[it], bl, acc[jt][it], 0, 0, 0);
                acc[jt][it] = __builtin_amdgcn_mfma_f32_16x16x32_f16(wlo[it], bh, acc[jt][it], 0, 0, 0);
            }
        }
    }
}

__device__ __forceinline__ void epilogue_gelu(f32x4 acc[4][4], const float* __restrict__ bias,
                                              u32* act, int lane) {
    const int q = lane >> 4, r = lane & 15;
    #pragma unroll
    for (int it = 0; it < 4; it++) {
        int mb = it * 16 + q * 4;
        float c0 = bias[mb], c1 = bias[mb + 1], c2 = bias[mb + 2], c3 = bias[mb + 3];
        #pragma unroll
        for (int jt = 0; jt < 4; jt++) {
            f32x4 d = acc[jt][it];
            u32* dst = act + (jt * 16 + r) * STR + mb;
            // descale 2^-16 (A,B both x256), gelu, re-scale 2^8 for the next layer
            dst[0] = packhl(gelu_f(fmaf(d[0], 0x1p-16f, c0)) * 256.0f);
            dst[1] = packhl(gelu_f(fmaf(d[1], 0x1p-16f, c1)) * 256.0f);
            dst[2] = packhl(gelu_f(fmaf(d[2], 0x1p-16f, c2)) * 256.0f);
            dst[3] = packhl(gelu_f(fmaf(d[3], 0x1p-16f, c3)) * 256.0f);
        }
    }
}

// ================= single self-contained kernel: encode + MFMA MLP chain =================
__global__ void __launch_bounds__(64) nerf_all(
    const float* __restrict__ pos, const float* __restrict__ dirs,
    const int* __restrict__ iter, const float* __restrict__ tables,
    const int* __restrict__ shifts,
    const float* __restrict__ W1, const float* __restrict__ b1,
    const float* __restrict__ W2, const float* __restrict__ b2,
    const float* __restrict__ W3, const float* __restrict__ b3,
    const float* __restrict__ W4, const float* __restrict__ b4,
    const float* __restrict__ R1, const float* __restrict__ rb1,
    const float* __restrict__ R2, const float* __restrict__ rb2,
    const float* __restrict__ R3, const float* __restrict__ rb3,
    float* __restrict__ out, int n)
{
    __shared__ u32 act[64 * STR + 16];   // +16 pad: R1-layer q>=2 predicated reads stay in-bounds
    const int lane = threadIdx.x;
    const int i = blockIdx.x * 64 + lane;
    const bool valid = (i < n);
    u32* myrow = act + lane * STR;

    float px = 0.f, py = 0.f, pz = 0.f;
    if (valid) { px = pos[3*i]; py = pos[3*i+1]; pz = pos[3*i+2]; }

    #pragma unroll
    for (int k = 51; k < 64; k++) myrow[k] = 0u;
    myrow[48] = packhl(px * 256.0f);
    myrow[49] = packhl(py * 256.0f);
    myrow[50] = packhl(pz * 256.0f);

    #pragma unroll 2
    for (int l = 0; l < LVLS; l++) {
        float sc, wl; window_scale(l, iter, sc, wl);
        float f0, f1;
        hash_level(px, py, pz, sc, wl, shifts[3*l], shifts[3*l+1], shifts[3*l+2],
                   tables + 2 * ((size_t)l * CAPN), f0, f1);
        myrow[2*l]     = (u32)f2h(f0 * 256.0f) << 16;
        myrow[2*l + 1] = (u32)f2h(f1 * 256.0f) << 16;
    }
    __syncthreads();

    f32x4 acc[4][4];
    mfma_layer<2, false>(W1, 51, 64, 0, act, lane, acc);
    epilogue_gelu(acc, b1, act, lane);
    __syncthreads();
    mfma_layer<2, false>(W2, 64, 64, 0, act, lane, acc);
    epilogue_gelu(acc, b2, act, lane);
    __syncthreads();
    mfma_layer<2, false>(W3, 64, 64, 0, act, lane, acc);
    epilogue_gelu(acc, b3, act, lane);
    __syncthreads();

    // density (scalar dot over X3; myrow holds 256*x -> descale by 2^-8)
    {
        float t = 0.f;
        #pragma unroll 8
        for (int k = 0; k < 64; k++) {
            float xv = unpackhl(myrow[k]);
            t = fmaf(xv, W4[(size_t)k * 65], t);
        }
        float s = fmaf(t, 0x1p-8f, b4[0]);
        if (valid) out[(size_t)3 * n + i] = fmaxf(s, 0.f) + log1pf(expf(-fabsf(s)));
    }
    mfma_layer<2, false>(W4, 64, 65, 1, act, lane, acc);   // W4 cols 1..64
    epilogue_gelu(acc, b4 + 1, act, lane);

    // SH -> feats 64..79 (stored x256)
    {
        float dx = 0.f, dy = 0.f, dz = 0.f;
        if (valid) { dx = dirs[3*i]; dy = dirs[3*i+1]; dz = dirs[3*i+2]; }
        float xx = dx*dx, yy = dy*dy, zz = dz*dz;
        float sh[16];
        sh[0]  = 0.28209479177387814f;
        sh[1]  = -0.48860251190291987f * dy;
        sh[2]  = 0.48860251190291987f * dz;
        sh[3]  = -0.48860251190291987f * dx;
        sh[4]  = 1.0925484305920792f * dx * dy;
        sh[5]  = -1.0925484305920792f * dy * dz;
        sh[6]  = 0.94617469575756f * zz - 0.31539156525252f;
        sh[7]  = -1.0925484305920792f * dx * dz;
        sh[8]  = 0.5462742152960396f * (xx - yy);
        sh[9]  = -0.5900435899266435f * dy * (3.0f * xx - yy);
        sh[10] = 2.890611442640554f * dx * dy * dz;
        sh[11] = -0.4570457994644657f * dy * (4.0f * zz - xx - yy);
        sh[12] = 0.37317633259011546f * dz * (2.0f * zz - 3.0f * xx - 3.0f * yy);
        sh[13] = -0.4570457994644657f * dx * (4.0f * zz - xx - yy);
        sh[14] = 1.445305721320277f * dz * (xx - yy);
        sh[15] = -0.5900435899266435f * dx * (xx - 3.0f * yy);
        #pragma unroll
        for (int j = 0; j < 16; j++) myrow[64 + j] = packhl(sh[j] * 256.0f);
    }
    __syncthreads();

    mfma_layer<3, true>(R1, 80, 64, 0, act, lane, acc);
    epilogue_gelu(acc, rb1, act, lane);
    __syncthreads();
    mfma_layer<2, false>(R2, 64, 64, 0, act, lane, acc);
    epilogue_gelu(acc, rb2, act, lane);
    __syncthreads();

    // R3 (scalar) + sigmoid (myrow holds 256*x -> descale by 2^-8)
    {
        float t0 = 0.f, t1 = 0.f, t2 = 0.f;
        #pragma unroll 8
        for (int k = 0; k < 64; k++) {
            float xv = unpackhl(myrow[k]);
            t0 = fmaf(xv, R3[(size_t)k * 3 + 0], t0);
            t1 = fmaf(xv, R3[(size_t)k * 3 + 1], t1);
            t2 = fmaf(xv, R3[(size_t)k * 3 + 2], t2);
        }
        float y0 = fmaf(t0, 0x1p-8f, rb3[0]);
        float y1 = fmaf(t1, 0x1p-8f, rb3[1]);
        float y2 = fmaf(t2, 0x1p-8f, rb3[2]);
        if (valid) {
            out[(size_t)3 * i + 0] = sigmoid_f(y0);
            out[(size_t)3 * i + 1] = sigmoid_f(y1);
            out[(size_t)3 * i + 2] = sigmoid_f(y2);
        }
    }
}

extern "C" void kernel_launch(void* const* d_in, const int* in_sizes, int n_in,
                              void* d_out, int out_size, void* d_ws, size_t ws_size,
                              hipStream_t stream) {
    (void)d_ws; (void)ws_size;
    int n = in_sizes[0] / 3;
    int grid = (n + 63) / 64;

    nerf_all<<<grid, 64, 0, stream>>>(
        (const float*)d_in[0], (const float*)d_in[1], (const int*)d_in[2],
        (const float*)d_in[3], (const int*)d_in[4],
        (const float*)d_in[5],  (const float*)d_in[6],
        (const float*)d_in[7],  (const float*)d_in[8],
        (const float*)d_in[9],  (const float*)d_in[10],
        (const float*)d_in[11], (const float*)d_in[12],
        (const float*)d_in[13], (const float*)d_in[14],
        (const float*)d_in[15], (const float*)d_in[16],
        (const float*)d_in[17], (const float*)d_in[18],
        (float*)d_out, n);
}